// Round 1
// baseline (868.785 us; speedup 1.0000x reference)
//
#include <hip/hip_runtime.h>
#include <cstddef>

// Dims from the reference
#define F_IN    208
#define HID     131
#define G3      393    // 3*HID
#define DD      255
#define NOUT    17
#define N_SEQ   128
#define T_BATCH 4096

// GRU kernel decomposition: KS k-slices per gate-row-triple
#define KS      4
#define KLEN    36            // ceil(131/4) padded to multiple of 4 (float4 aligned)
#define HPAD    (KS * KLEN)   // 144
#define NTH     (KS * HID)    // 524 active threads
#define GRU_BLK 576           // 9 waves

// Scratch in module device globals (fully overwritten every call; no ws dependence)
__device__ float g_gi[N_SEQ * G3];
__device__ float g_x[N_SEQ * HID];
__device__ float g_dummy[512];

__device__ __forceinline__ float sigmoidf_(float x) {
  return 1.0f / (1.0f + __expf(-x));
}

// ---------------------------------------------------------------------------
// Kernel 1: gi[n][g] = b_ih[g] + sum_f history[n][4095][f] * W_ih[g][f]
// Only batch lane T_BATCH-1 feeds the output (GRU lanes are independent and
// the reference emits h_new[-1]). Also touch-prefetches W_hh into every
// XCD's L2 for the single-block GRU kernel that follows.
// ---------------------------------------------------------------------------
__global__ __launch_bounds__(512) void gi_kernel(const float* __restrict__ hist,
                                                 const float* __restrict__ W_ih,
                                                 const float* __restrict__ b_ih,
                                                 const float* __restrict__ W_hh) {
  __shared__ __align__(16) float s_hist[F_IN];
  const int n = blockIdx.x;
  const int tid = threadIdx.x;

  const float* row = hist + ((size_t)n * T_BATCH + (T_BATCH - 1)) * F_IN;
  if (tid < F_IN / 4) {  // 52 float4 = 208 floats; row start is 832B-aligned
    reinterpret_cast<float4*>(s_hist)[tid] = reinterpret_cast<const float4*>(row)[tid];
  }
  __syncthreads();

  if (tid < G3) {
    const float4* w4 = reinterpret_cast<const float4*>(W_ih + (size_t)tid * F_IN);
    const float4* h4 = reinterpret_cast<const float4*>(s_hist);
    float acc = b_ih[tid];
#pragma unroll
    for (int i = 0; i < F_IN / 4; ++i) {
      const float4 w = w4[i];
      const float4 h = h4[i];
      acc = fmaf(w.x, h.x, acc); acc = fmaf(w.y, h.y, acc);
      acc = fmaf(w.z, h.z, acc); acc = fmaf(w.w, h.w, acc);
    }
    g_gi[n * G3 + tid] = acc;
  }

  // L2 warm-up for W_hh (one float per 64B line); guarded write defeats DCE.
  float acc2 = 0.0f;
  const int nlines = (G3 * HID + 15) / 16;  // 3218
  for (int i = tid; i < nlines; i += 512) acc2 += W_hh[i * 16];
  if (acc2 == 1234.5678f) g_dummy[tid] = acc2;
}

// ---------------------------------------------------------------------------
// Kernel 2: serial 128-step GRU for the single surviving lane.
// 576 threads: thread (s,u) = (tid/131, tid%131) owns k-slice s of the three
// gate rows {u, 131+u, 262+u} of W_hh, held in registers (loaded once).
// Per step: partial dot-products -> LDS -> barrier -> thread u reduces its 4
// k-slices for all 3 gates and applies the nonlinearity -> barrier.
// ---------------------------------------------------------------------------
__global__ __launch_bounds__(GRU_BLK, 3) void gru_kernel(const float* __restrict__ W_hh,
                                                         const float* __restrict__ b_hh) {
  __shared__ __align__(16) float s_h[HPAD];       // h padded with zeros to 144
  __shared__ float s_pr[NTH + 4], s_pz[NTH + 4], s_pn[NTH + 4];

  const int tid = threadIdx.x;
  const int s = tid / HID;        // k-slice 0..3 (for active threads)
  const int u = tid - s * HID;    // hidden unit 0..130
  const bool active = (tid < NTH);

  // Load this thread's weight slices into registers (statically indexed).
  float wr[KLEN], wz[KLEN], wn[KLEN];
  if (active) {
#pragma unroll
    for (int i = 0; i < KLEN; ++i) {
      const int k = s * KLEN + i;
      const bool ok = (k < HID);
      wr[i] = ok ? W_hh[(size_t)u * HID + k] : 0.0f;
      wz[i] = ok ? W_hh[(size_t)(HID + u) * HID + k] : 0.0f;
      wn[i] = ok ? W_hh[(size_t)(2 * HID + u) * HID + k] : 0.0f;
    }
  }
  float bhr = 0.0f, bhz = 0.0f, bhn = 0.0f;
  if (tid < HID) {
    bhr = b_hh[tid];
    bhz = b_hh[HID + tid];
    bhn = b_hh[2 * HID + tid];
  }
  for (int i = tid; i < HPAD; i += GRU_BLK) s_h[i] = 0.0f;
  __syncthreads();

  for (int n = 0; n < N_SEQ; ++n) {
    // Issue gi loads early; they resolve during the partial-dot phase.
    float gir = 0.0f, giz = 0.0f, gin = 0.0f;
    if (tid < HID) {
      gir = g_gi[n * G3 + tid];
      giz = g_gi[n * G3 + HID + tid];
      gin = g_gi[n * G3 + 2 * HID + tid];
    }

    if (active) {
      float pr = 0.0f, pz = 0.0f, pn = 0.0f;
      const float4* h4 = reinterpret_cast<const float4*>(s_h) + s * (KLEN / 4);
#pragma unroll
      for (int q = 0; q < KLEN / 4; ++q) {
        const float4 hv = h4[q];  // wave-uniform address within a wave -> LDS broadcast
        pr = fmaf(wr[4*q+0], hv.x, pr); pz = fmaf(wz[4*q+0], hv.x, pz); pn = fmaf(wn[4*q+0], hv.x, pn);
        pr = fmaf(wr[4*q+1], hv.y, pr); pz = fmaf(wz[4*q+1], hv.y, pz); pn = fmaf(wn[4*q+1], hv.y, pn);
        pr = fmaf(wr[4*q+2], hv.z, pr); pz = fmaf(wz[4*q+2], hv.z, pz); pn = fmaf(wn[4*q+2], hv.z, pn);
        pr = fmaf(wr[4*q+3], hv.w, pr); pz = fmaf(wz[4*q+3], hv.w, pz); pn = fmaf(wn[4*q+3], hv.w, pn);
      }
      s_pr[tid] = pr; s_pz[tid] = pz; s_pn[tid] = pn;
    }
    __syncthreads();

    if (tid < HID) {
      const float ghr = bhr + s_pr[tid] + s_pr[tid + HID] + s_pr[tid + 2*HID] + s_pr[tid + 3*HID];
      const float ghz = bhz + s_pz[tid] + s_pz[tid + HID] + s_pz[tid + 2*HID] + s_pz[tid + 3*HID];
      const float ghn = bhn + s_pn[tid] + s_pn[tid + HID] + s_pn[tid + 2*HID] + s_pn[tid + 3*HID];
      const float r  = sigmoidf_(gir + ghr);
      const float z  = sigmoidf_(giz + ghz);
      const float nn = tanhf(gin + r * ghn);
      const float hprev = s_h[tid];
      const float hnew  = (1.0f - z) * nn + z * hprev;
      s_h[tid] = hnew;              // no one reads s_h between the two barriers
      g_x[n * HID + tid] = hnew;
    }
    __syncthreads();
  }
}

// ---------------------------------------------------------------------------
// Kernel 3: 6-layer MLP, one block per sequence row. Activations ping-pong in
// LDS; each thread owns one output neuron per layer (row-sequential weight
// reads stay L1-resident).
// ---------------------------------------------------------------------------
template <int K, int NO, bool RELU>
__device__ __forceinline__ void mlp_layer(const float* __restrict__ W,
                                          const float* __restrict__ b,
                                          const float* __restrict__ s_in,
                                          float* __restrict__ s_out,
                                          int tid) {
  if (tid < NO) {
    const float* w = W + (size_t)tid * K;
    float acc = b[tid];
#pragma unroll 4
    for (int k = 0; k < K; ++k) acc = fmaf(s_in[k], w[k], acc);
    s_out[tid] = RELU ? fmaxf(acc, 0.0f) : acc;
  }
  __syncthreads();
}

__global__ __launch_bounds__(256) void mlp_kernel(const float* __restrict__ W1, const float* __restrict__ b1,
                                                  const float* __restrict__ W2, const float* __restrict__ b2,
                                                  const float* __restrict__ W3, const float* __restrict__ b3,
                                                  const float* __restrict__ W4, const float* __restrict__ b4,
                                                  const float* __restrict__ W5, const float* __restrict__ b5,
                                                  const float* __restrict__ W6, const float* __restrict__ b6,
                                                  float* __restrict__ out) {
  __shared__ float s_a[DD + 1], s_b[DD + 1];
  const int n = blockIdx.x;
  const int tid = threadIdx.x;

  if (tid < HID) s_a[tid] = g_x[n * HID + tid];
  __syncthreads();

  mlp_layer<HID, DD, true>(W1, b1, s_a, s_b, tid);
  mlp_layer<DD,  DD, true>(W2, b2, s_b, s_a, tid);
  mlp_layer<DD,  DD, true>(W3, b3, s_a, s_b, tid);
  mlp_layer<DD,  DD, true>(W4, b4, s_b, s_a, tid);
  mlp_layer<DD,  DD, true>(W5, b5, s_a, s_b, tid);

  if (tid < NOUT) {
    const float* w = W6 + (size_t)tid * DD;
    float acc = b6[tid];
#pragma unroll 4
    for (int k = 0; k < DD; ++k) acc = fmaf(s_b[k], w[k], acc);
    out[n * NOUT + tid] = acc;
  }
}

// ---------------------------------------------------------------------------
extern "C" void kernel_launch(void* const* d_in, const int* in_sizes, int n_in,
                              void* d_out, int out_size, void* d_ws, size_t ws_size,
                              hipStream_t stream) {
  const float* hist = (const float*)d_in[0];
  const float* W_ih = (const float*)d_in[1];
  const float* W_hh = (const float*)d_in[2];
  const float* b_ih = (const float*)d_in[3];
  const float* b_hh = (const float*)d_in[4];
  const float* W1 = (const float*)d_in[5];  const float* b1 = (const float*)d_in[6];
  const float* W2 = (const float*)d_in[7];  const float* b2 = (const float*)d_in[8];
  const float* W3 = (const float*)d_in[9];  const float* b3 = (const float*)d_in[10];
  const float* W4 = (const float*)d_in[11]; const float* b4 = (const float*)d_in[12];
  const float* W5 = (const float*)d_in[13]; const float* b5 = (const float*)d_in[14];
  const float* W6 = (const float*)d_in[15]; const float* b6 = (const float*)d_in[16];
  float* out = (float*)d_out;

  gi_kernel<<<N_SEQ, 512, 0, stream>>>(hist, W_ih, b_ih, W_hh);
  gru_kernel<<<1, GRU_BLK, 0, stream>>>(W_hh, b_hh);
  mlp_kernel<<<N_SEQ, 256, 0, stream>>>(W1, b1, W2, b2, W3, b3, W4, b4, W5, b5, W6, b6, out);
}

// Round 2
// 647.131 us; speedup vs baseline: 1.3425x; 1.3425x over previous
//
#include <hip/hip_runtime.h>
#include <cstddef>

// Dims from the reference
#define F_IN    208
#define HID     131
#define G3      393    // 3*HID
#define DD      255
#define NOUT    17
#define N_SEQ   128
#define T_BATCH 4096

// GRU kernel decomposition: KS k-slices per gate-row-triple
#define KS      4
#define KLEN    36            // ceil(131/4) padded to multiple of 4 (float4 aligned)
#define HPAD    (KS * KLEN)   // 144
#define NTH     (KS * HID)    // 524 active threads
#define GRU_BLK 576           // 9 waves

// MLP: transposed zero-padded weights, [k][o] with o-stride 256
#define MKS     4             // k-split ways in the MLP block
#define OPAD    256
#define KP1     144           // padded K for layer 1 (131 -> 144 = 4*36)
#define KP      256           // padded K for layers 2..6 (255 -> 256)
#define WT_OFF1 0
#define WT_OFF2 (KP1 * OPAD)                    // 36864
#define WT_OFF3 (WT_OFF2 + KP * OPAD)           // 102400
#define WT_OFF4 (WT_OFF3 + KP * OPAD)           // 167936
#define WT_OFF5 (WT_OFF4 + KP * OPAD)           // 233472
#define WT_OFF6 (WT_OFF5 + KP * OPAD)           // 299008
#define WT_TOT  (WT_OFF6 + KP * OPAD)           // 364544

// Scratch in module device globals (fully overwritten every call)
__device__ float g_gi[N_SEQ * G3];
__device__ float g_x[N_SEQ * HID];
__device__ float g_Wt[WT_TOT];
__device__ float g_dummy[512];

__device__ __forceinline__ float sigmoidf_(float x) {
  return 1.0f / (1.0f + __expf(-x));
}

// ---------------------------------------------------------------------------
// Kernel 0: transpose + zero-pad the six MLP weight matrices into g_Wt.
// Layout: g_Wt[off + k*256 + o] = W[o][k] (0 outside the valid region).
// Writes coalesced; reads uncoalesced but tiny (1.4 MB total).
// ---------------------------------------------------------------------------
__global__ __launch_bounds__(256) void prep_kernel(const float* __restrict__ W1,
                                                   const float* __restrict__ W2,
                                                   const float* __restrict__ W3,
                                                   const float* __restrict__ W4,
                                                   const float* __restrict__ W5,
                                                   const float* __restrict__ W6) {
  int idx = blockIdx.x * 256 + threadIdx.x;
  if (idx >= WT_TOT) return;
  if (idx < WT_OFF2) {                       // layer 1: [255][131] -> [144][256]
    const int k = idx >> 8, o = idx & 255;
    g_Wt[idx] = (o < DD && k < HID) ? W1[o * HID + k] : 0.0f;
    return;
  }
  const int r = idx - WT_OFF2;
  const int m = r >> 16;                     // 0..4 -> layers 2..6
  const int t = r & 65535;
  const int k = t >> 8, o = t & 255;
  const float* W = (m == 0) ? W2 : (m == 1) ? W3 : (m == 2) ? W4 : (m == 3) ? W5 : W6;
  const int no = (m == 4) ? NOUT : DD;
  g_Wt[idx] = (o < no && k < DD) ? W[o * DD + k] : 0.0f;
}

// ---------------------------------------------------------------------------
// Kernel 1: gi[n][g] = b_ih[g] + sum_f history[n][4095][f] * W_ih[g][f]
// Only batch lane T_BATCH-1 feeds the output (GRU lanes are independent and
// the reference emits h_new[-1]). Also touch-prefetches W_hh into every
// XCD's L2 for the single-block GRU kernel that follows.
// ---------------------------------------------------------------------------
__global__ __launch_bounds__(512) void gi_kernel(const float* __restrict__ hist,
                                                 const float* __restrict__ W_ih,
                                                 const float* __restrict__ b_ih,
                                                 const float* __restrict__ W_hh) {
  __shared__ __align__(16) float s_hist[F_IN];
  const int n = blockIdx.x;
  const int tid = threadIdx.x;

  const float* row = hist + ((size_t)n * T_BATCH + (T_BATCH - 1)) * F_IN;
  if (tid < F_IN / 4) {
    reinterpret_cast<float4*>(s_hist)[tid] = reinterpret_cast<const float4*>(row)[tid];
  }
  __syncthreads();

  if (tid < G3) {
    const float4* w4 = reinterpret_cast<const float4*>(W_ih + (size_t)tid * F_IN);
    const float4* h4 = reinterpret_cast<const float4*>(s_hist);
    float acc = b_ih[tid];
#pragma unroll
    for (int i = 0; i < F_IN / 4; ++i) {
      const float4 w = w4[i];
      const float4 h = h4[i];
      acc = fmaf(w.x, h.x, acc); acc = fmaf(w.y, h.y, acc);
      acc = fmaf(w.z, h.z, acc); acc = fmaf(w.w, h.w, acc);
    }
    g_gi[n * G3 + tid] = acc;
  }

  // L2 warm-up for W_hh (one float per 64B line); guarded write defeats DCE.
  float acc2 = 0.0f;
  const int nlines = (G3 * HID + 15) / 16;
  for (int i = tid; i < nlines; i += 512) acc2 += W_hh[i * 16];
  if (acc2 == 1234.5678f) g_dummy[tid] = acc2;
}

// ---------------------------------------------------------------------------
// Kernel 2: serial 128-step GRU for the single surviving lane. (unchanged)
// ---------------------------------------------------------------------------
__global__ __launch_bounds__(GRU_BLK, 3) void gru_kernel(const float* __restrict__ W_hh,
                                                         const float* __restrict__ b_hh) {
  __shared__ __align__(16) float s_h[HPAD];
  __shared__ float s_pr[NTH + 4], s_pz[NTH + 4], s_pn[NTH + 4];

  const int tid = threadIdx.x;
  const int s = tid / HID;
  const int u = tid - s * HID;
  const bool active = (tid < NTH);

  float wr[KLEN], wz[KLEN], wn[KLEN];
  if (active) {
#pragma unroll
    for (int i = 0; i < KLEN; ++i) {
      const int k = s * KLEN + i;
      const bool ok = (k < HID);
      wr[i] = ok ? W_hh[(size_t)u * HID + k] : 0.0f;
      wz[i] = ok ? W_hh[(size_t)(HID + u) * HID + k] : 0.0f;
      wn[i] = ok ? W_hh[(size_t)(2 * HID + u) * HID + k] : 0.0f;
    }
  }
  float bhr = 0.0f, bhz = 0.0f, bhn = 0.0f;
  if (tid < HID) {
    bhr = b_hh[tid];
    bhz = b_hh[HID + tid];
    bhn = b_hh[2 * HID + tid];
  }
  for (int i = tid; i < HPAD; i += GRU_BLK) s_h[i] = 0.0f;
  __syncthreads();

  for (int n = 0; n < N_SEQ; ++n) {
    float gir = 0.0f, giz = 0.0f, gin = 0.0f;
    if (tid < HID) {
      gir = g_gi[n * G3 + tid];
      giz = g_gi[n * G3 + HID + tid];
      gin = g_gi[n * G3 + 2 * HID + tid];
    }

    if (active) {
      float pr = 0.0f, pz = 0.0f, pn = 0.0f;
      const float4* h4 = reinterpret_cast<const float4*>(s_h) + s * (KLEN / 4);
#pragma unroll
      for (int q = 0; q < KLEN / 4; ++q) {
        const float4 hv = h4[q];
        pr = fmaf(wr[4*q+0], hv.x, pr); pz = fmaf(wz[4*q+0], hv.x, pz); pn = fmaf(wn[4*q+0], hv.x, pn);
        pr = fmaf(wr[4*q+1], hv.y, pr); pz = fmaf(wz[4*q+1], hv.y, pz); pn = fmaf(wn[4*q+1], hv.y, pn);
        pr = fmaf(wr[4*q+2], hv.z, pr); pz = fmaf(wz[4*q+2], hv.z, pz); pn = fmaf(wn[4*q+2], hv.z, pn);
        pr = fmaf(wr[4*q+3], hv.w, pr); pz = fmaf(wz[4*q+3], hv.w, pz); pn = fmaf(wn[4*q+3], hv.w, pn);
      }
      s_pr[tid] = pr; s_pz[tid] = pz; s_pn[tid] = pn;
    }
    __syncthreads();

    if (tid < HID) {
      const float ghr = bhr + s_pr[tid] + s_pr[tid + HID] + s_pr[tid + 2*HID] + s_pr[tid + 3*HID];
      const float ghz = bhz + s_pz[tid] + s_pz[tid + HID] + s_pz[tid + 2*HID] + s_pz[tid + 3*HID];
      const float ghn = bhn + s_pn[tid] + s_pn[tid + HID] + s_pn[tid + 2*HID] + s_pn[tid + 3*HID];
      const float r  = sigmoidf_(gir + ghr);
      const float z  = sigmoidf_(giz + ghz);
      const float nn = tanhf(gin + r * ghn);
      const float hprev = s_h[tid];
      const float hnew  = (1.0f - z) * nn + z * hprev;
      s_h[tid] = hnew;
      g_x[n * HID + tid] = hnew;
    }
    __syncthreads();
  }
}

// ---------------------------------------------------------------------------
// Kernel 3: 6-layer MLP, one 1024-thread block per row. Thread (ks,o) with
// ks=tid>>8, o=tid&255 computes the ks-th k-slice of output o: activation
// slice via float4 LDS reads, weights via COALESCED loads of the transposed
// g_Wt (lane o -> address stride 4B). 4 partials reduced through LDS.
// Single activation buffer s_x[256] (zero-padded; pad entries never written).
// ---------------------------------------------------------------------------
template <int KPAD, bool RELU, int NO>
__device__ __forceinline__ void mlp_layerT(const float* __restrict__ Wt,
                                           const float* __restrict__ b,
                                           float* __restrict__ s_x,
                                           float* __restrict__ s_part,
                                           int ks, int o, int tid,
                                           float* __restrict__ gout, int n) {
  constexpr int KL = KPAD / MKS;         // 36 or 64
  const float4* x4 = reinterpret_cast<const float4*>(s_x) + ks * (KL / 4);
  const float* w = Wt + (ks * KL) * OPAD + o;
  float acc = 0.0f;
#pragma unroll
  for (int q = 0; q < KL / 4; ++q) {
    const float4 xv = x4[q];
    acc = fmaf(xv.x, w[(4*q+0) * OPAD], acc);
    acc = fmaf(xv.y, w[(4*q+1) * OPAD], acc);
    acc = fmaf(xv.z, w[(4*q+2) * OPAD], acc);
    acc = fmaf(xv.w, w[(4*q+3) * OPAD], acc);
  }
  s_part[ks * OPAD + o] = acc;
  __syncthreads();
  if (tid < NO) {
    const float v = b[tid] + s_part[tid] + s_part[OPAD + tid]
                  + s_part[2 * OPAD + tid] + s_part[3 * OPAD + tid];
    if (RELU) s_x[tid] = fmaxf(v, 0.0f);
    else      gout[n * NOUT + tid] = v;   // final layer writes straight out
  }
  __syncthreads();
}

__global__ __launch_bounds__(1024) void mlp_kernel(const float* __restrict__ b1,
                                                   const float* __restrict__ b2,
                                                   const float* __restrict__ b3,
                                                   const float* __restrict__ b4,
                                                   const float* __restrict__ b5,
                                                   const float* __restrict__ b6,
                                                   float* __restrict__ out) {
  __shared__ __align__(16) float s_x[OPAD];
  __shared__ float s_part[MKS * OPAD];
  const int n = blockIdx.x;
  const int tid = threadIdx.x;
  const int ks = tid >> 8;
  const int o  = tid & 255;

  if (tid < OPAD) s_x[tid] = (tid < HID) ? g_x[n * HID + tid] : 0.0f;
  __syncthreads();

  mlp_layerT<KP1, true,  DD>(g_Wt + WT_OFF1, b1, s_x, s_part, ks, o, tid, out, n);
  mlp_layerT<KP,  true,  DD>(g_Wt + WT_OFF2, b2, s_x, s_part, ks, o, tid, out, n);
  mlp_layerT<KP,  true,  DD>(g_Wt + WT_OFF3, b3, s_x, s_part, ks, o, tid, out, n);
  mlp_layerT<KP,  true,  DD>(g_Wt + WT_OFF4, b4, s_x, s_part, ks, o, tid, out, n);
  mlp_layerT<KP,  true,  DD>(g_Wt + WT_OFF5, b5, s_x, s_part, ks, o, tid, out, n);
  mlp_layerT<KP,  false, NOUT>(g_Wt + WT_OFF6, b6, s_x, s_part, ks, o, tid, out, n);
}

// ---------------------------------------------------------------------------
extern "C" void kernel_launch(void* const* d_in, const int* in_sizes, int n_in,
                              void* d_out, int out_size, void* d_ws, size_t ws_size,
                              hipStream_t stream) {
  const float* hist = (const float*)d_in[0];
  const float* W_ih = (const float*)d_in[1];
  const float* W_hh = (const float*)d_in[2];
  const float* b_ih = (const float*)d_in[3];
  const float* b_hh = (const float*)d_in[4];
  const float* W1 = (const float*)d_in[5];  const float* b1 = (const float*)d_in[6];
  const float* W2 = (const float*)d_in[7];  const float* b2 = (const float*)d_in[8];
  const float* W3 = (const float*)d_in[9];  const float* b3 = (const float*)d_in[10];
  const float* W4 = (const float*)d_in[11]; const float* b4 = (const float*)d_in[12];
  const float* W5 = (const float*)d_in[13]; const float* b5 = (const float*)d_in[14];
  const float* W6 = (const float*)d_in[15]; const float* b6 = (const float*)d_in[16];
  float* out = (float*)d_out;

  prep_kernel<<<(WT_TOT + 255) / 256, 256, 0, stream>>>(W1, W2, W3, W4, W5, W6);
  gi_kernel<<<N_SEQ, 512, 0, stream>>>(hist, W_ih, b_ih, W_hh);
  gru_kernel<<<1, GRU_BLK, 0, stream>>>(W_hh, b_hh);
  mlp_kernel<<<N_SEQ, 1024, 0, stream>>>(b1, b2, b3, b4, b5, b6, out);
}